// Round 4
// baseline (502.840 us; speedup 1.0000x reference)
//
#include <hip/hip_runtime.h>
#include <hip/hip_bf16.h>

typedef __bf16 bf16_t;
typedef __bf16 bf16x8 __attribute__((ext_vector_type(8)));
typedef __bf16 bf16x4 __attribute__((ext_vector_type(4)));
typedef float  f32x4  __attribute__((ext_vector_type(4)));

#define NB  8
#define NC  256
#define NC8 32
#define NN  4096

#define MFMA16(a, b, c) __builtin_amdgcn_mfma_f32_16x16x32_bf16((a), (b), (c), 0, 0, 0)

// ---------------------------------------------------------------------------
// Kernel 0: fp32 -> bf16 for all three weight matrices in one launch.
// ---------------------------------------------------------------------------
__global__ __launch_bounds__(256) void cvt_all(const float* __restrict__ wq,
                                               const float* __restrict__ wk,
                                               const float* __restrict__ wv,
                                               bf16_t* __restrict__ wqb,
                                               bf16_t* __restrict__ wkb,
                                               bf16_t* __restrict__ wvb) {
    int i = blockIdx.x * 256 + threadIdx.x;   // 0..20479
    const float* src; bf16_t* dst; int off;
    if (i < 2048)      { src = wq; dst = wqb; off = i; }
    else if (i < 4096) { src = wk; dst = wkb; off = i - 2048; }
    else               { src = wv; dst = wvb; off = i - 4096; }
    float4 v = reinterpret_cast<const float4*>(src)[off];
    bf16x4 o;
    o[0] = (bf16_t)v.x; o[1] = (bf16_t)v.y; o[2] = (bf16_t)v.z; o[3] = (bf16_t)v.w;
    reinterpret_cast<bf16x4*>(dst)[off] = o;
}

// ---------------------------------------------------------------------------
// Kernel 1: x fp32 [b][c][n] -> xt bf16 [b][n][c] (transpose + downconvert)
// ---------------------------------------------------------------------------
__global__ __launch_bounds__(256) void transpose_x(const float* __restrict__ x,
                                                   bf16_t* __restrict__ xt) {
    __shared__ bf16_t tile[64][72];
    const int b  = blockIdx.z;
    const int c0 = blockIdx.y * 64;
    const int n0 = blockIdx.x * 64;
    const int t  = threadIdx.x;

    const int cl = t >> 4;
    const int nl = (t & 15) * 4;
    for (int p = 0; p < 4; ++p) {
        const int cc = cl + 16 * p;
        float4 v = *reinterpret_cast<const float4*>(
            x + ((size_t)b * NC + c0 + cc) * NN + n0 + nl);
        bf16x4 bv;
        bv[0] = (bf16_t)v.x; bv[1] = (bf16_t)v.y; bv[2] = (bf16_t)v.z; bv[3] = (bf16_t)v.w;
        *reinterpret_cast<bf16x4*>(&tile[cc][nl]) = bv;
    }
    __syncthreads();
    const int nb  = t >> 3;
    const int cl2 = (t & 7) * 8;
    for (int p = 0; p < 2; ++p) {
        const int nn = nb + 32 * p;
        bf16x8 v;
        for (int i = 0; i < 8; ++i) v[i] = tile[cl2 + i][nn];
        *reinterpret_cast<bf16x8*>(
            xt + ((size_t)b * NN + n0 + nn) * NC + c0 + cl2) = v;
    }
}

// ---------------------------------------------------------------------------
// Kernel 2: fused q/k/v projections per (b, n-tile of 64).
// ---------------------------------------------------------------------------
__global__ __launch_bounds__(256) void proj_all(const bf16_t* __restrict__ xt,
                                                const bf16_t* __restrict__ wq,
                                                const float* __restrict__ bq,
                                                const bf16_t* __restrict__ wk,
                                                const float* __restrict__ bk,
                                                const bf16_t* __restrict__ wv,
                                                const float* __restrict__ bv,
                                                bf16_t* __restrict__ ft,
                                                bf16_t* __restrict__ gt,
                                                bf16_t* __restrict__ h) {
    const int bx = blockIdx.x;
    const int b  = bx >> 6;
    const int n0 = (bx & 63) * 64;
    const int w    = threadIdx.x >> 6;
    const int lane = threadIdx.x & 63;
    const int q    = lane >> 4;
    const int r    = lane & 15;

    const bf16_t* xb = xt + (size_t)b * NN * NC;

    // ---- q/k part
    {
        const bf16_t* xrow = xb + (size_t)(n0 + 16 * w + r) * NC;
        f32x4 accq[2], acck[2];
        for (int ot = 0; ot < 2; ++ot) {
            accq[ot] = (f32x4){0.f, 0.f, 0.f, 0.f};
            acck[ot] = (f32x4){0.f, 0.f, 0.f, 0.f};
        }
        for (int k0 = 0; k0 < NC; k0 += 32) {
            bf16x8 a = *reinterpret_cast<const bf16x8*>(xrow + k0 + 8 * q);
            for (int ot = 0; ot < 2; ++ot) {
                bf16x8 fq = *reinterpret_cast<const bf16x8*>(wq + (size_t)(16 * ot + r) * NC + k0 + 8 * q);
                accq[ot] = MFMA16(a, fq, accq[ot]);
                bf16x8 fk = *reinterpret_cast<const bf16x8*>(wk + (size_t)(16 * ot + r) * NC + k0 + 8 * q);
                acck[ot] = MFMA16(a, fk, acck[ot]);
            }
        }
        for (int ot = 0; ot < 2; ++ot) {
            const int o = 16 * ot + r;
            const float biq = bq[o];
            const float bik = bk[o];
            for (int i = 0; i < 4; ++i) {
                const int n = n0 + 16 * w + 4 * q + i;
                ft[((size_t)b * NN + n) * NC8 + o] = (bf16_t)(accq[ot][i] + biq);
                gt[((size_t)b * NN + n) * NC8 + o] = (bf16_t)(acck[ot][i] + bik);
            }
        }
    }

    // ---- v part: xt B-fragments shared across 4 c-tiles
    f32x4 vacc[4][4];
    for (int ct = 0; ct < 4; ++ct)
        for (int nt = 0; nt < 4; ++nt) vacc[ct][nt] = (f32x4){0.f, 0.f, 0.f, 0.f};

    for (int k0 = 0; k0 < NC; k0 += 32) {
        bf16x8 bfr[4];
        for (int nt = 0; nt < 4; ++nt)
            bfr[nt] = *reinterpret_cast<const bf16x8*>(
                xb + (size_t)(n0 + 16 * nt + r) * NC + k0 + 8 * q);
        for (int ct = 0; ct < 4; ++ct) {
            bf16x8 a = *reinterpret_cast<const bf16x8*>(
                wv + (size_t)(64 * ct + 16 * w + r) * NC + k0 + 8 * q);
            for (int nt = 0; nt < 4; ++nt)
                vacc[ct][nt] = MFMA16(a, bfr[nt], vacc[ct][nt]);
        }
    }
    for (int ct = 0; ct < 4; ++ct) {
        for (int nt = 0; nt < 4; ++nt) {
            for (int i = 0; i < 4; ++i) {
                const int c = 64 * ct + 16 * w + 4 * q + i;
                const int n = n0 + 16 * nt + r;
                h[((size_t)b * NC + c) * NN + n] = (bf16_t)(vacc[ct][nt][i] + bv[c]);
            }
        }
    }
}

// ---------------------------------------------------------------------------
// Kernel 3: attention. One barrier/iter (double-buffered P), software-pipelined
// af/hf global loads, XOR-swizzled P layout (stride 64, balanced banks).
// ---------------------------------------------------------------------------
__global__ __launch_bounds__(256, 2) void attn(const bf16_t* __restrict__ ft,
                                               const bf16_t* __restrict__ gt,
                                               const bf16_t* __restrict__ h,
                                               float* __restrict__ out) {
    __shared__ bf16_t P[2][64 * 64];
    __shared__ float  l_lds[64];

    const int bx = blockIdx.x;     // 8 * 64
    const int b  = bx >> 6;
    const int m0 = (bx & 63) * 64;
    const int tid  = threadIdx.x;
    const int w    = tid >> 6;
    const int lane = tid & 63;
    const int q    = lane >> 4;
    const int r    = lane & 15;

    if (tid < 64) l_lds[tid] = 0.f;

    bf16x8 qf[4];
    for (int mt = 0; mt < 4; ++mt)
        qf[mt] = *reinterpret_cast<const bf16x8*>(
            gt + ((size_t)b * NN + m0 + 16 * mt + r) * NC8 + 8 * q);

    f32x4 acc[4][4];
    for (int ct = 0; ct < 4; ++ct)
        for (int mt = 0; mt < 4; ++mt) acc[ct][mt] = (f32x4){0.f, 0.f, 0.f, 0.f};
    float lp[4] = {0.f, 0.f, 0.f, 0.f};

    const bf16_t* fb = ft + (size_t)b * NN * NC8;
    const bf16_t* hb = h + (size_t)b * NC * NN;
    const f32x4 zero = (f32x4){0.f, 0.f, 0.f, 0.f};

    // ---- prologue: h(0), S(0), af(1)
    bf16x8 hbuf[2][8];
    for (int half = 0; half < 2; ++half)
        for (int ct = 0; ct < 4; ++ct)
            hbuf[0][half * 4 + ct] = *reinterpret_cast<const bf16x8*>(
                hb + (size_t)(64 * w + 16 * ct + r) * NN + 32 * half + 8 * q);
    bf16x8 af = *reinterpret_cast<const bf16x8*>(fb + (size_t)(16 * w + r) * NC8 + 8 * q);
    f32x4 s[4];
    for (int mt = 0; mt < 4; ++mt) s[mt] = MFMA16(af, qf[mt], zero);
    bf16x8 af_fly = *reinterpret_cast<const bf16x8*>(fb + (size_t)(64 + 16 * w + r) * NC8 + 8 * q);

    for (int i = 0; i < 64; ++i) {
        const int cur = i & 1, nxt = cur ^ 1;
        bf16_t* Pb = P[cur];

        // ---- exp phase: write P[cur] (stragglers may still read P[nxt]) — safe
        for (int mt = 0; mt < 4; ++mt) {
            float e0 = __expf(s[mt][0]);
            float e1 = __expf(s[mt][1]);
            float e2 = __expf(s[mt][2]);
            float e3 = __expf(s[mt][3]);
            lp[mt] += (e0 + e1) + (e2 + e3);
            bf16x4 pv;
            pv[0] = (bf16_t)e0; pv[1] = (bf16_t)e1; pv[2] = (bf16_t)e2; pv[3] = (bf16_t)e3;
            const int row = 16 * mt + r;   // col m_loc = 16mt+r, rows n_loc = 16w+4q+reg
            *reinterpret_cast<bf16x4*>(
                &Pb[(row << 6) + (((2 * w + (q >> 1)) ^ (r & 7)) << 3) + 4 * (q & 1)]) = pv;
        }
        __syncthreads();   // P[cur] visible; drains prefetches issued last iter

        // ---- prefetch h(i+1): in flight across O(i)+S(i+1)+exp(i+1)
        if (i < 63) {
            const int n1 = (i + 1) * 64;
            for (int half = 0; half < 2; ++half)
                for (int ct = 0; ct < 4; ++ct)
                    hbuf[nxt][half * 4 + ct] = *reinterpret_cast<const bf16x8*>(
                        hb + (size_t)(64 * w + 16 * ct + r) * NN + n1 + 32 * half + 8 * q);
        }

        // ---- O phase: acc += h(i) x P[cur]
        for (int half = 0; half < 2; ++half) {
            bf16x8 pf[4];
            for (int mt = 0; mt < 4; ++mt) {
                const int row = 16 * mt + r;
                pf[mt] = *reinterpret_cast<const bf16x8*>(
                    &Pb[(row << 6) + (((4 * half + q) ^ (r & 7)) << 3)]);
            }
            for (int ct = 0; ct < 4; ++ct)
                for (int mt = 0; mt < 4; ++mt)
                    acc[ct][mt] = MFMA16(hbuf[cur][half * 4 + ct], pf[mt], acc[ct][mt]);
        }

        // ---- S(i+1) + issue af(i+2)
        if (i < 63) {
            af = af_fly;
            for (int mt = 0; mt < 4; ++mt) s[mt] = MFMA16(af, qf[mt], zero);
            const int n2 = (i + 2 < 64 ? i + 2 : 63) * 64;
            af_fly = *reinterpret_cast<const bf16x8*>(
                fb + (size_t)(n2 + 16 * w + r) * NC8 + 8 * q);
        }
    }

    // ---- reduce l partials
    __syncthreads();
    for (int mt = 0; mt < 4; ++mt) {
        float v = lp[mt];
        v += __shfl_xor(v, 16);
        v += __shfl_xor(v, 32);
        if (q == 0) atomicAdd(&l_lds[16 * mt + r], v);
    }
    __syncthreads();

    // ---- epilogue: out[b][c][m] = acc / l[m]  (fp32)
    for (int ct = 0; ct < 4; ++ct) {
        for (int mt = 0; mt < 4; ++mt) {
            const int m = m0 + 16 * mt + r;
            const float linv = 1.0f / l_lds[16 * mt + r];
            for (int i = 0; i < 4; ++i) {
                const int c = 64 * w + 16 * ct + 4 * q + i;
                out[((size_t)b * NC + c) * NN + m] = acc[ct][mt][i] * linv;
            }
        }
    }
}

extern "C" void kernel_launch(void* const* d_in, const int* in_sizes, int n_in,
                              void* d_out, int out_size, void* d_ws, size_t ws_size,
                              hipStream_t stream) {
    const float* x  = (const float*)d_in[0];
    const float* wq = (const float*)d_in[1];
    const float* bq = (const float*)d_in[2];
    const float* wk = (const float*)d_in[3];
    const float* bk = (const float*)d_in[4];
    const float* wv = (const float*)d_in[5];
    const float* bv = (const float*)d_in[6];
    float* out = (float*)d_out;

    bf16_t* xt  = (bf16_t*)d_ws;                     // [B][N][C]
    bf16_t* ft  = xt + (size_t)NB * NN * NC;         // [B][N][32]
    bf16_t* gt  = ft + (size_t)NB * NN * NC8;        // [B][N][32]
    bf16_t* hb  = gt + (size_t)NB * NN * NC8;        // [B][C][N]
    bf16_t* wqb = hb + (size_t)NB * NC * NN;         // [32][256]
    bf16_t* wkb = wqb + (size_t)NC8 * NC;            // [32][256]
    bf16_t* wvb = wkb + (size_t)NC8 * NC;            // [256][256]

    cvt_all<<<80, 256, 0, stream>>>(wq, wk, wv, wqb, wkb, wvb);
    transpose_x<<<dim3(NN / 64, NC / 64, NB), 256, 0, stream>>>(x, xt);
    proj_all<<<NB * (NN / 64), 256, 0, stream>>>(xt, wqb, bq, wkb, bk, wvb, bv, ft, gt, hb);
    attn<<<NB * (NN / 64), 256, 0, stream>>>(ft, gt, hb, out);
}

// Round 5
// 250.222 us; speedup vs baseline: 2.0096x; 2.0096x over previous
//
#include <hip/hip_runtime.h>
#include <hip/hip_bf16.h>

typedef __bf16 bf16_t;
typedef __bf16 bf16x8 __attribute__((ext_vector_type(8)));
typedef __bf16 bf16x4 __attribute__((ext_vector_type(4)));
typedef float  f32x4  __attribute__((ext_vector_type(4)));

#define NB  8
#define NC  256
#define NC8 32
#define NN  4096

#define MFMA16(a, b, c) __builtin_amdgcn_mfma_f32_16x16x32_bf16((a), (b), (c), 0, 0, 0)

// ---------------------------------------------------------------------------
// Kernel 0: fp32 -> bf16 for all three weight matrices in one launch.
// ---------------------------------------------------------------------------
__global__ __launch_bounds__(256) void cvt_all(const float* __restrict__ wq,
                                               const float* __restrict__ wk,
                                               const float* __restrict__ wv,
                                               bf16_t* __restrict__ wqb,
                                               bf16_t* __restrict__ wkb,
                                               bf16_t* __restrict__ wvb) {
    int i = blockIdx.x * 256 + threadIdx.x;   // 0..20479
    const float* src; bf16_t* dst; int off;
    if (i < 2048)      { src = wq; dst = wqb; off = i; }
    else if (i < 4096) { src = wk; dst = wkb; off = i - 2048; }
    else               { src = wv; dst = wvb; off = i - 4096; }
    float4 v = reinterpret_cast<const float4*>(src)[off];
    bf16x4 o;
    o[0] = (bf16_t)v.x; o[1] = (bf16_t)v.y; o[2] = (bf16_t)v.z; o[3] = (bf16_t)v.w;
    reinterpret_cast<bf16x4*>(dst)[off] = o;
}

// ---------------------------------------------------------------------------
// Kernel 1: x fp32 [b][c][n] -> xt bf16 [b][n][c] (transpose + downconvert)
// ---------------------------------------------------------------------------
__global__ __launch_bounds__(256) void transpose_x(const float* __restrict__ x,
                                                   bf16_t* __restrict__ xt) {
    __shared__ bf16_t tile[64][72];
    const int b  = blockIdx.z;
    const int c0 = blockIdx.y * 64;
    const int n0 = blockIdx.x * 64;
    const int t  = threadIdx.x;

    const int cl = t >> 4;
    const int nl = (t & 15) * 4;
    for (int p = 0; p < 4; ++p) {
        const int cc = cl + 16 * p;
        float4 v = *reinterpret_cast<const float4*>(
            x + ((size_t)b * NC + c0 + cc) * NN + n0 + nl);
        bf16x4 bv;
        bv[0] = (bf16_t)v.x; bv[1] = (bf16_t)v.y; bv[2] = (bf16_t)v.z; bv[3] = (bf16_t)v.w;
        *reinterpret_cast<bf16x4*>(&tile[cc][nl]) = bv;
    }
    __syncthreads();
    const int nb  = t >> 3;
    const int cl2 = (t & 7) * 8;
    for (int p = 0; p < 2; ++p) {
        const int nn = nb + 32 * p;
        bf16x8 v;
        for (int i = 0; i < 8; ++i) v[i] = tile[cl2 + i][nn];
        *reinterpret_cast<bf16x8*>(
            xt + ((size_t)b * NN + n0 + nn) * NC + c0 + cl2) = v;
    }
}

// ---------------------------------------------------------------------------
// Kernel 2: fused q/k/v projections per (b, n-tile of 64).
// ---------------------------------------------------------------------------
__global__ __launch_bounds__(256) void proj_all(const bf16_t* __restrict__ xt,
                                                const bf16_t* __restrict__ wq,
                                                const float* __restrict__ bq,
                                                const bf16_t* __restrict__ wk,
                                                const float* __restrict__ bk,
                                                const bf16_t* __restrict__ wv,
                                                const float* __restrict__ bv,
                                                bf16_t* __restrict__ ft,
                                                bf16_t* __restrict__ gt,
                                                bf16_t* __restrict__ h) {
    const int bx = blockIdx.x;
    const int b  = bx >> 6;
    const int n0 = (bx & 63) * 64;
    const int w    = threadIdx.x >> 6;
    const int lane = threadIdx.x & 63;
    const int q    = lane >> 4;
    const int r    = lane & 15;

    const bf16_t* xb = xt + (size_t)b * NN * NC;

    // ---- q/k part
    {
        const bf16_t* xrow = xb + (size_t)(n0 + 16 * w + r) * NC;
        f32x4 accq[2], acck[2];
        for (int ot = 0; ot < 2; ++ot) {
            accq[ot] = (f32x4){0.f, 0.f, 0.f, 0.f};
            acck[ot] = (f32x4){0.f, 0.f, 0.f, 0.f};
        }
        for (int k0 = 0; k0 < NC; k0 += 32) {
            bf16x8 a = *reinterpret_cast<const bf16x8*>(xrow + k0 + 8 * q);
            for (int ot = 0; ot < 2; ++ot) {
                bf16x8 fq = *reinterpret_cast<const bf16x8*>(wq + (size_t)(16 * ot + r) * NC + k0 + 8 * q);
                accq[ot] = MFMA16(a, fq, accq[ot]);
                bf16x8 fk = *reinterpret_cast<const bf16x8*>(wk + (size_t)(16 * ot + r) * NC + k0 + 8 * q);
                acck[ot] = MFMA16(a, fk, acck[ot]);
            }
        }
        for (int ot = 0; ot < 2; ++ot) {
            const int o = 16 * ot + r;
            const float biq = bq[o];
            const float bik = bk[o];
            for (int i = 0; i < 4; ++i) {
                const int n = n0 + 16 * w + 4 * q + i;
                ft[((size_t)b * NN + n) * NC8 + o] = (bf16_t)(accq[ot][i] + biq);
                gt[((size_t)b * NN + n) * NC8 + o] = (bf16_t)(acck[ot][i] + bik);
            }
        }
    }

    // ---- v part: xt B-fragments shared across 4 c-tiles
    f32x4 vacc[4][4];
    for (int ct = 0; ct < 4; ++ct)
        for (int nt = 0; nt < 4; ++nt) vacc[ct][nt] = (f32x4){0.f, 0.f, 0.f, 0.f};

    for (int k0 = 0; k0 < NC; k0 += 32) {
        bf16x8 bfr[4];
        for (int nt = 0; nt < 4; ++nt)
            bfr[nt] = *reinterpret_cast<const bf16x8*>(
                xb + (size_t)(n0 + 16 * nt + r) * NC + k0 + 8 * q);
        for (int ct = 0; ct < 4; ++ct) {
            bf16x8 a = *reinterpret_cast<const bf16x8*>(
                wv + (size_t)(64 * ct + 16 * w + r) * NC + k0 + 8 * q);
            for (int nt = 0; nt < 4; ++nt)
                vacc[ct][nt] = MFMA16(a, bfr[nt], vacc[ct][nt]);
        }
    }
    for (int ct = 0; ct < 4; ++ct) {
        for (int nt = 0; nt < 4; ++nt) {
            for (int i = 0; i < 4; ++i) {
                const int c = 64 * ct + 16 * w + 4 * q + i;
                const int n = n0 + 16 * nt + r;
                h[((size_t)b * NC + c) * NN + n] = (bf16_t)(vacc[ct][nt][i] + bv[c]);
            }
        }
    }
}

// ---------------------------------------------------------------------------
// Kernel 3: attention. One barrier per n-chunk; P double-buffered in LDS
// (XOR-swizzled); h prefetch double-buffered in REGISTERS with compile-time
// indices (hA/hB) — never a runtime-indexed register array (scratch trap!).
// ---------------------------------------------------------------------------
__global__ __launch_bounds__(256, 2) void attn(const bf16_t* __restrict__ ft,
                                               const bf16_t* __restrict__ gt,
                                               const bf16_t* __restrict__ h,
                                               float* __restrict__ out) {
    __shared__ bf16_t P[2][64 * 64];
    __shared__ float  l_lds[64];

    const int bx = blockIdx.x;     // 8 * 64
    const int b  = bx >> 6;
    const int m0 = (bx & 63) * 64;
    const int tid  = threadIdx.x;
    const int w    = tid >> 6;
    const int lane = tid & 63;
    const int q    = lane >> 4;
    const int r    = lane & 15;

    if (tid < 64) l_lds[tid] = 0.f;

    bf16x8 qf[4];
#pragma unroll
    for (int mt = 0; mt < 4; ++mt)
        qf[mt] = *reinterpret_cast<const bf16x8*>(
            gt + ((size_t)b * NN + m0 + 16 * mt + r) * NC8 + 8 * q);

    f32x4 acc[4][4];
#pragma unroll
    for (int ct = 0; ct < 4; ++ct)
#pragma unroll
        for (int mt = 0; mt < 4; ++mt) acc[ct][mt] = (f32x4){0.f, 0.f, 0.f, 0.f};
    float lp[4] = {0.f, 0.f, 0.f, 0.f};

    const bf16_t* fb = ft + (size_t)b * NN * NC8;
    const bf16_t* hb = h + (size_t)b * NC * NN;
    const f32x4 zero = (f32x4){0.f, 0.f, 0.f, 0.f};

    // h row base for this thread (c = 64w+16ct+r), column offset added per chunk
    const bf16_t* hrow[4];
#pragma unroll
    for (int ct = 0; ct < 4; ++ct)
        hrow[ct] = hb + (size_t)(64 * w + 16 * ct + r) * NN + 8 * q;

    bf16x8 hA[8], hB[8];
    // ---- prologue: hA = h(chunk 0), s = S(0), af_fly = ft(chunk 1)
#pragma unroll
    for (int half = 0; half < 2; ++half)
#pragma unroll
        for (int ct = 0; ct < 4; ++ct)
            hA[half * 4 + ct] = *reinterpret_cast<const bf16x8*>(hrow[ct] + 32 * half);
    bf16x8 af = *reinterpret_cast<const bf16x8*>(fb + (size_t)(16 * w + r) * NC8 + 8 * q);
    f32x4 s[4];
#pragma unroll
    for (int mt = 0; mt < 4; ++mt) s[mt] = MFMA16(af, qf[mt], zero);
    bf16x8 af_fly = *reinterpret_cast<const bf16x8*>(fb + (size_t)(64 + 16 * w + r) * NC8 + 8 * q);

    const int swW = ((2 * w + (q >> 1)) << 3);   // write block pre-shift
    const int rq  = (r & 7) << 3;

    for (int ii = 0; ii < 64; ii += 2) {
        // ================= chunk ii : uses hA, stages into P[0] ===========
        {
            bf16_t* Pb = P[0];
#pragma unroll
            for (int mt = 0; mt < 4; ++mt) {
                float e0 = __expf(s[mt][0]);
                float e1 = __expf(s[mt][1]);
                float e2 = __expf(s[mt][2]);
                float e3 = __expf(s[mt][3]);
                lp[mt] += (e0 + e1) + (e2 + e3);
                bf16x4 pv;
                pv[0] = (bf16_t)e0; pv[1] = (bf16_t)e1; pv[2] = (bf16_t)e2; pv[3] = (bf16_t)e3;
                const int row = 16 * mt + r;
                *reinterpret_cast<bf16x4*>(
                    &Pb[(row << 6) + (swW ^ rq) + 4 * (q & 1)]) = pv;
            }
            __syncthreads();

            // prefetch hB = h(chunk ii+1)  (ii+1 <= 63 always)
            const int n1 = (ii + 1) * 64;
#pragma unroll
            for (int half = 0; half < 2; ++half)
#pragma unroll
                for (int ct = 0; ct < 4; ++ct)
                    hB[half * 4 + ct] = *reinterpret_cast<const bf16x8*>(hrow[ct] + n1 + 32 * half);

            // O += hA x P[0]
#pragma unroll
            for (int half = 0; half < 2; ++half) {
                bf16x8 pf[4];
#pragma unroll
                for (int mt = 0; mt < 4; ++mt) {
                    const int row = 16 * mt + r;
                    pf[mt] = *reinterpret_cast<const bf16x8*>(
                        &Pb[(row << 6) + ((((4 * half + q) << 3) ^ rq))]);
                }
#pragma unroll
                for (int ct = 0; ct < 4; ++ct)
#pragma unroll
                    for (int mt = 0; mt < 4; ++mt)
                        acc[ct][mt] = MFMA16(hA[half * 4 + ct], pf[mt], acc[ct][mt]);
            }

            // s = S(ii+1); issue af(ii+2)
            af = af_fly;
#pragma unroll
            for (int mt = 0; mt < 4; ++mt) s[mt] = MFMA16(af, qf[mt], zero);
            const int n2 = (ii + 2 < 64 ? ii + 2 : 63) * 64;
            af_fly = *reinterpret_cast<const bf16x8*>(
                fb + (size_t)(n2 + 16 * w + r) * NC8 + 8 * q);
        }

        // ================= chunk ii+1 : uses hB, stages into P[1] =========
        {
            bf16_t* Pb = P[1];
#pragma unroll
            for (int mt = 0; mt < 4; ++mt) {
                float e0 = __expf(s[mt][0]);
                float e1 = __expf(s[mt][1]);
                float e2 = __expf(s[mt][2]);
                float e3 = __expf(s[mt][3]);
                lp[mt] += (e0 + e1) + (e2 + e3);
                bf16x4 pv;
                pv[0] = (bf16_t)e0; pv[1] = (bf16_t)e1; pv[2] = (bf16_t)e2; pv[3] = (bf16_t)e3;
                const int row = 16 * mt + r;
                *reinterpret_cast<bf16x4*>(
                    &Pb[(row << 6) + (swW ^ rq) + 4 * (q & 1)]) = pv;
            }
            __syncthreads();

            // prefetch hA = h(chunk ii+2), clamped (redundant reload on last iter)
            const int n1 = (ii + 2 < 64 ? ii + 2 : 63) * 64;
#pragma unroll
            for (int half = 0; half < 2; ++half)
#pragma unroll
                for (int ct = 0; ct < 4; ++ct)
                    hA[half * 4 + ct] = *reinterpret_cast<const bf16x8*>(hrow[ct] + n1 + 32 * half);

            // O += hB x P[1]
#pragma unroll
            for (int half = 0; half < 2; ++half) {
                bf16x8 pf[4];
#pragma unroll
                for (int mt = 0; mt < 4; ++mt) {
                    const int row = 16 * mt + r;
                    pf[mt] = *reinterpret_cast<const bf16x8*>(
                        &Pb[(row << 6) + ((((4 * half + q) << 3) ^ rq))]);
                }
#pragma unroll
                for (int ct = 0; ct < 4; ++ct)
#pragma unroll
                    for (int mt = 0; mt < 4; ++mt)
                        acc[ct][mt] = MFMA16(hB[half * 4 + ct], pf[mt], acc[ct][mt]);
            }

            // s = S(ii+2); issue af(ii+3). Last iter computes a dead s — harmless.
            af = af_fly;
#pragma unroll
            for (int mt = 0; mt < 4; ++mt) s[mt] = MFMA16(af, qf[mt], zero);
            const int n2 = (ii + 3 < 64 ? ii + 3 : 63) * 64;
            af_fly = *reinterpret_cast<const bf16x8*>(
                fb + (size_t)(n2 + 16 * w + r) * NC8 + 8 * q);
        }
    }

    // ---- reduce l partials
    __syncthreads();
#pragma unroll
    for (int mt = 0; mt < 4; ++mt) {
        float v = lp[mt];
        v += __shfl_xor(v, 16);
        v += __shfl_xor(v, 32);
        if (q == 0) atomicAdd(&l_lds[16 * mt + r], v);
    }
    __syncthreads();

    // ---- epilogue: out[b][c][m] = acc / l[m]  (fp32)
#pragma unroll
    for (int ct = 0; ct < 4; ++ct) {
#pragma unroll
        for (int mt = 0; mt < 4; ++mt) {
            const int m = m0 + 16 * mt + r;
            const float linv = 1.0f / l_lds[16 * mt + r];
#pragma unroll
            for (int i = 0; i < 4; ++i) {
                const int c = 64 * w + 16 * ct + 4 * q + i;
                out[((size_t)b * NC + c) * NN + m] = acc[ct][mt][i] * linv;
            }
        }
    }
}

extern "C" void kernel_launch(void* const* d_in, const int* in_sizes, int n_in,
                              void* d_out, int out_size, void* d_ws, size_t ws_size,
                              hipStream_t stream) {
    const float* x  = (const float*)d_in[0];
    const float* wq = (const float*)d_in[1];
    const float* bq = (const float*)d_in[2];
    const float* wk = (const float*)d_in[3];
    const float* bk = (const float*)d_in[4];
    const float* wv = (const float*)d_in[5];
    const float* bv = (const float*)d_in[6];
    float* out = (float*)d_out;

    bf16_t* xt  = (bf16_t*)d_ws;                     // [B][N][C]
    bf16_t* ft  = xt + (size_t)NB * NN * NC;         // [B][N][32]
    bf16_t* gt  = ft + (size_t)NB * NN * NC8;        // [B][N][32]
    bf16_t* hb  = gt + (size_t)NB * NN * NC8;        // [B][C][N]
    bf16_t* wqb = hb + (size_t)NB * NC * NN;         // [32][256]
    bf16_t* wkb = wqb + (size_t)NC8 * NC;            // [32][256]
    bf16_t* wvb = wkb + (size_t)NC8 * NC;            // [256][256]

    cvt_all<<<80, 256, 0, stream>>>(wq, wk, wv, wqb, wkb, wvb);
    transpose_x<<<dim3(NN / 64, NC / 64, NB), 256, 0, stream>>>(x, xt);
    proj_all<<<NB * (NN / 64), 256, 0, stream>>>(xt, wqb, bq, wkb, bk, wvb, bv, ft, gt, hb);
    attn<<<NB * (NN / 64), 256, 0, stream>>>(ft, gt, hb, out);
}